// Round 2
// 424.022 us; speedup vs baseline: 1.1747x; 1.1747x over previous
//
#include <hip/hip_runtime.h>
#include <math.h>

// Problem constants
#define TTOK   16384
#define HDIM   4096
#define ENUM   64
#define KTOP   6
#define GNUM   8
#define TGK    3
#define BBATCH 4
#define SSEQ   4096
#define ALPHAC 0.001f

// GEMM tiling
#define KSPLIT 4
#define KSL    (HDIM / KSPLIT)   // 1024 k per slice
#define TM     256               // tokens per block
#define TE     32                // experts per block
#define BK     32                // k per LDS iter
#define NIT    (KSL / BK)        // 32 iterations

#define AS3(p) ((__attribute__((address_space(3))) void*)(p))
#define AS1(p) ((const __attribute__((address_space(1))) void*)(p))

typedef float wvec16 __attribute__((ext_vector_type(16)));

// ---------------------------------------------------------------------------
// Kernel 0: pack W[64][4096] -> Wp[k4][e][4]  (k-chunks of 4, expert-major)
// a wave's per-kq W slice (4 experts x 4 k) is 64 B contiguous -> s_load_dwordx16
// ---------------------------------------------------------------------------
__global__ __launch_bounds__(256)
void pack_w(const float* __restrict__ W, float* __restrict__ Wp) {
    const int gid = blockIdx.x * 256 + threadIdx.x;   // 0..65535
    const int k4 = gid >> 6, e = gid & 63;
    float4 v = *(const float4*)(W + (size_t)e * HDIM + k4 * 4);
    *(float4*)(Wp + (size_t)gid * 4) = v;
}

// ---------------------------------------------------------------------------
// Kernel 1: gate GEMM. Block = 256 tokens x 32 experts, 8 waves.
// Each wave: 4 experts x 256 tokens; lane holds 4 tokens (acc[4][4]).
// Per kq: 4 ds_read_b128 (X) + one 64B uniform W load + 64 fmacs.
// X staged via global_load_lds with XOR float4-slot swizzle (bank-conflict-free
// ds_read_b128 on the read side, linear LDS dest on the write side).
// ---------------------------------------------------------------------------
__global__ __launch_bounds__(512, 4)
void gate_gemm(const float* __restrict__ X, const float* __restrict__ Wp,
               float* __restrict__ lp) {
    __shared__ __align__(16) float Xs[2][TM * BK];   // 2 x 32 KB

    const int tid = threadIdx.x;
    const int w   = __builtin_amdgcn_readfirstlane(tid >> 6);  // wave 0..7
    const int l   = tid & 63;
    const int lm7 = l & 7;

    // XCD-grouped decode: the eh=0/1 pair of a (tile,slice) reads identical X;
    // map them to consecutive work on the same XCD so L2 catches the re-read.
    const int id     = blockIdx.x;                 // 0..511 (8 XCDs x 64)
    const int linear = (id & 7) * 64 + (id >> 3);
    const int eh     = linear & 1;                 // expert half
    const int ts     = linear >> 1;                // 0..255
    const int tile   = ts & 63;
    const int slice  = ts >> 6;                    // 0..3
    const int T0     = tile * TM;
    const int k0     = slice * KSL;
    const int E0     = eh * TE + w * 4;            // this wave's 4 experts

    // staging: thread (w,l), round r fills LDS chunk c = r*512 + w*64 + l
    // (chunk = 16B). Row t = c>>3, slot s = c&7 = l&7, t&7 = l>>3.
    // Slot s of row t holds global k4-chunk (s ^ (t&7))  -> pre-swizzled source.
    const int trow = l >> 3;
    const int kswz = ((l & 7) ^ trow) << 2;        // float offset
    const float* gs = X + (size_t)(T0 + w * 8 + trow) * HDIM + k0 + kswz;

#define STAGE(buf_, it_) do {                                                   \
    const size_t go_ = (size_t)(it_) * BK;                                      \
    _Pragma("unroll")                                                           \
    for (int r_ = 0; r_ < 4; ++r_)                                              \
        __builtin_amdgcn_global_load_lds(                                       \
            AS1(gs + (size_t)r_ * 64 * HDIM + go_),                             \
            AS3(&Xs[buf_][r_ * 2048 + w * 256]), 16, 0, 0);                     \
} while (0)

    float acc[4][4];
#pragma unroll
    for (int g = 0; g < 4; ++g)
#pragma unroll
        for (int j = 0; j < 4; ++j) acc[g][j] = 0.f;

    const int k4base = k0 >> 2;

    STAGE(0, 0);   // prologue

    for (int it = 0; it < NIT; ++it) {
        __syncthreads();   // drains this iter's staging (vmcnt) + barrier
        if (it + 1 < NIT) STAGE((it + 1) & 1, it + 1);

        const float* xb = Xs[it & 1];
        const int k4it  = k4base + it * (BK / 4);
#pragma unroll
        for (int kq = 0; kq < 8; ++kq) {
            // 64 B of W for 4 experts x 4 k, wave-uniform -> scalar load
            const wvec16 wv = *(const wvec16*)(Wp + ((size_t)(k4it + kq) * ENUM + E0) * 4);
            const int slot = (kq ^ lm7) << 2;      // swizzled float4 slot
#pragma unroll
            for (int g = 0; g < 4; ++g) {
                const float4 xv = *(const float4*)(xb + (g * 64 + l) * BK + slot);
#pragma unroll
                for (int j = 0; j < 4; ++j) {
                    acc[g][j] = fmaf(xv.x, wv[4 * j + 0], acc[g][j]);
                    acc[g][j] = fmaf(xv.y, wv[4 * j + 1], acc[g][j]);
                    acc[g][j] = fmaf(xv.z, wv[4 * j + 2], acc[g][j]);
                    acc[g][j] = fmaf(xv.w, wv[4 * j + 3], acc[g][j]);
                }
            }
        }
    }

    float* dst = lp + (size_t)slice * TTOK * ENUM + (size_t)(T0 + l) * ENUM + E0;
#pragma unroll
    for (int g = 0; g < 4; ++g)
        *(float4*)(dst + (size_t)g * 64 * ENUM) =
            make_float4(acc[g][0], acc[g][1], acc[g][2], acc[g][3]);
#undef STAGE
}

// ---------------------------------------------------------------------------
// Kernel 2: thread-per-token router. 64 tokens/block, 256 blocks. (unchanged)
// ---------------------------------------------------------------------------
#define RTOK 64
__global__ __launch_bounds__(256)
void router_topk(const float* __restrict__ lp,
                 float* __restrict__ out_idx, float* __restrict__ out_w,
                 float* __restrict__ ssum_g, int* __restrict__ cnt_g) {
    __shared__ float Ls[RTOK * 67];
    __shared__ float s_m[RTOK], s_inv[RTOK];
    __shared__ float s_ssum[ENUM];
    __shared__ int   s_cnt[ENUM];

    const int tid = threadIdx.x;
    const int t0  = blockIdx.x * RTOK;
    if (tid < ENUM) { s_cnt[tid] = 0; s_ssum[tid] = 0.f; }

#pragma unroll
    for (int r = 0; r < 4; ++r) {
        const int q  = r * 256 + tid;
        const int t  = q >> 4, c4 = q & 15;
        const size_t base = (size_t)(t0 + t) * ENUM + c4 * 4;
        float4 v = *(const float4*)(lp + base);
#pragma unroll
        for (int h = 1; h < KSPLIT; ++h) {
            float4 u = *(const float4*)(lp + (size_t)h * TTOK * ENUM + base);
            v.x += u.x; v.y += u.y; v.z += u.z; v.w += u.w;
        }
        float* d = Ls + t * 67 + c4 * 4;
        d[0] = v.x; d[1] = v.y; d[2] = v.z; d[3] = v.w;
    }
    __syncthreads();

    if (tid < RTOK) {
        const float* row = Ls + tid * 67;

        float gm[GNUM];
#pragma unroll
        for (int g = 0; g < GNUM; ++g) {
            float mg = row[g * 8];
#pragma unroll
            for (int j = 1; j < 8; ++j) mg = fmaxf(mg, row[g * 8 + j]);
            gm[g] = mg;
        }
        float m = gm[0];
#pragma unroll
        for (int g = 1; g < GNUM; ++g) m = fmaxf(m, gm[g]);

        int selmask = 0;
#pragma unroll
        for (int g = 0; g < GNUM; ++g) {
            int rank = 0;
#pragma unroll
            for (int g2 = 0; g2 < GNUM; ++g2)
                rank += (gm[g2] > gm[g]) || (gm[g2] == gm[g] && g2 < g);
            selmask |= (rank < TGK) << g;
        }

        float v0=-1.f,v1=-1.f,v2=-1.f,v3=-1.f,v4=-1.f,v5=-1.f;
        float i0=0.f,i1=0.f,i2=0.f,i3=0.f,i4=0.f,i5=0.f;
        float s = 0.f;
#pragma unroll
        for (int e = 0; e < ENUM; ++e) {
            const float ex = __expf(row[e] - m);
            s += ex;
            const float cand = ((selmask >> (e >> 3)) & 1) ? ex : -1.0f;
            const float fe = (float)e;
            const bool b0 = cand > v0, b1 = cand > v1, b2 = cand > v2,
                       b3 = cand > v3, b4 = cand > v4, b5 = cand > v5;
            v5 = b4 ? v4 : (b5 ? cand : v5);  i5 = b4 ? i4 : (b5 ? fe : i5);
            v4 = b3 ? v3 : (b4 ? cand : v4);  i4 = b3 ? i3 : (b4 ? fe : i4);
            v3 = b2 ? v2 : (b3 ? cand : v3);  i3 = b2 ? i2 : (b3 ? fe : i3);
            v2 = b1 ? v1 : (b2 ? cand : v2);  i2 = b1 ? i1 : (b2 ? fe : i2);
            v1 = b0 ? v0 : (b1 ? cand : v1);  i1 = b0 ? i0 : (b1 ? fe : i1);
            v0 = b0 ? cand : v0;              i0 = b0 ? fe : i0;
        }
        const float invw = 1.0f / (v0 + v1 + v2 + v3 + v4 + v5);
        const int t = t0 + tid;
        float* oi = out_idx + (size_t)t * KTOP;
        float* ow = out_w   + (size_t)t * KTOP;
        oi[0]=i0; oi[1]=i1; oi[2]=i2; oi[3]=i3; oi[4]=i4; oi[5]=i5;
        ow[0]=v0*invw; ow[1]=v1*invw; ow[2]=v2*invw;
        ow[3]=v3*invw; ow[4]=v4*invw; ow[5]=v5*invw;

        atomicAdd(&s_cnt[(int)i0], 1); atomicAdd(&s_cnt[(int)i1], 1);
        atomicAdd(&s_cnt[(int)i2], 1); atomicAdd(&s_cnt[(int)i3], 1);
        atomicAdd(&s_cnt[(int)i4], 1); atomicAdd(&s_cnt[(int)i5], 1);
        s_m[tid] = m; s_inv[tid] = 1.0f / s;
    }
    __syncthreads();

    {
        const int e = tid & 63, strip = tid >> 6;
        float acc = 0.f;
#pragma unroll
        for (int i = 0; i < RTOK / 4; ++i) {
            const int t = strip * (RTOK / 4) + i;
            acc += __expf(Ls[t * 67 + e] - s_m[t]) * s_inv[t];
        }
        atomicAdd(&s_ssum[e], acc);
    }
    __syncthreads();

    const int b = t0 / SSEQ;
    if (tid < ENUM) {
        atomicAdd(&ssum_g[b * ENUM + tid], s_ssum[tid]);
        atomicAdd(&cnt_g[b * ENUM + tid], s_cnt[tid]);
    }
}

// ---------------------------------------------------------------------------
// Kernel 3: aux loss (1 block) (unchanged)
// ---------------------------------------------------------------------------
__global__ __launch_bounds__(256)
void aux_loss(const float* __restrict__ ssum_g, const int* __restrict__ cnt_g,
              float* __restrict__ out_aux) {
    const int tid = threadIdx.x;
    float v = (float)cnt_g[tid] * (float)ENUM / ((float)SSEQ * (float)KTOP)
            * (ssum_g[tid] / (float)SSEQ);
#pragma unroll
    for (int off = 32; off; off >>= 1) v += __shfl_xor(v, off);
    __shared__ float red[4];
    if ((tid & 63) == 0) red[tid >> 6] = v;
    __syncthreads();
    if (tid == 0)
        out_aux[0] = (red[0] + red[1] + red[2] + red[3]) * (ALPHAC / (float)BBATCH);
}

// ---------------------------------------------------------------------------
extern "C" void kernel_launch(void* const* d_in, const int* in_sizes, int n_in,
                              void* d_out, int out_size, void* d_ws, size_t ws_size,
                              hipStream_t stream) {
    const float* X = (const float*)d_in[0];   // [4,4096,4096] fp32
    const float* W = (const float*)d_in[1];   // [64,4096] fp32

    float* out     = (float*)d_out;
    float* out_idx = out;
    float* out_w   = out + (size_t)TTOK * KTOP;
    float* out_aux = out + (size_t)2 * TTOK * KTOP;

    float* lp     = (float*)d_ws;                        // [4][T][64] = 16 MiB
    float* Wp     = lp + (size_t)KSPLIT * TTOK * ENUM;   // [1024][64][4] = 1 MiB
    float* ssum_g = Wp + (size_t)HDIM * ENUM;            // [4][64]
    int*   cnt_g  = (int*)(ssum_g + BBATCH * ENUM);      // [4][64]

    hipMemsetAsync(ssum_g, 0, BBATCH * ENUM * (sizeof(float) + sizeof(int)), stream);

    pack_w<<<(HDIM / 4) * ENUM / 256, 256, 0, stream>>>(W, Wp);
    gate_gemm<<<512, 512, 0, stream>>>(X, Wp, lp);
    router_topk<<<TTOK / RTOK, 256, 0, stream>>>(lp, out_idx, out_w, ssum_g, cnt_g);
    aux_loss<<<1, 256, 0, stream>>>(ssum_g, cnt_g, out_aux);
}

// Round 3
// 416.695 us; speedup vs baseline: 1.1954x; 1.0176x over previous
//
#include <hip/hip_runtime.h>
#include <math.h>

// Problem constants
#define TTOK   16384
#define HDIM   4096
#define ENUM   64
#define KTOP   6
#define GNUM   8
#define TGK    3
#define BBATCH 4
#define SSEQ   4096
#define ALPHAC 0.001f

// GEMM tiling
#define KSPLIT 8
#define KSL    (HDIM / KSPLIT)   // 512 k per slice
#define TM     256               // tokens per block
#define BK     32                // k per LDS iter
#define NIT    (KSL / BK)        // 16 iterations

#define AS3(p) ((__attribute__((address_space(3))) void*)(p))
#define AS1(p) ((const __attribute__((address_space(1))) void*)(p))

typedef float wvec16 __attribute__((ext_vector_type(16)));

// ---------------------------------------------------------------------------
// Kernel 0: pack W[64][4096] -> Wp[k4][e][4]  (k-chunks of 4, expert-major)
// a wave's per-kq W slice (8 experts x 4 k) is 128 B contiguous -> 2x s_load_dwordx16
// ---------------------------------------------------------------------------
__global__ __launch_bounds__(256)
void pack_w(const float* __restrict__ W, float* __restrict__ Wp) {
    const int gid = blockIdx.x * 256 + threadIdx.x;   // 0..65535
    const int k4 = gid >> 6, e = gid & 63;
    float4 v = *(const float4*)(W + (size_t)e * HDIM + k4 * 4);
    *(float4*)(Wp + (size_t)gid * 4) = v;
}

// ---------------------------------------------------------------------------
// Kernel 1: gate GEMM. Block = 256 tokens x ALL 64 experts, 8 waves.
// Wave w: experts 8w..8w+7, all 256 tokens; lane holds 4 tokens (acc[4][8]).
// Per kq: 4 ds_read_b128 (X) + one 128B uniform W load + 128 fmacs.
//   -> LDS demand 0.5 B/fmac (50% of LDS peak at full VALU), scalar W fetch
//      amortized over 256 VALU cycles.
// X staged via global_load_lds with XOR float4-slot swizzle (bank-conflict-free
// ds_read_b128 on the read side, linear LDS dest on the write side).
// ---------------------------------------------------------------------------
__global__ __launch_bounds__(512, 4)
void gate_gemm(const float* __restrict__ X, const float* __restrict__ Wp,
               float* __restrict__ lp) {
    __shared__ __align__(16) float Xs[2][TM * BK];   // 2 x 32 KB

    const int tid = threadIdx.x;
    const int w   = __builtin_amdgcn_readfirstlane(tid >> 6);  // wave 0..7
    const int l   = tid & 63;
    const int lm7 = l & 7;

    const int id    = blockIdx.x;                  // 0..511
    const int tile  = id >> 3;                     // 0..63
    const int slice = id & 7;                      // 0..7
    const int T0    = tile * TM;
    const int k0    = slice * KSL;
    const int E0    = w * 8;                       // this wave's 8 experts

    // staging: thread (w,l), round r fills LDS chunk c = r*512 + w*64 + l
    // (chunk = 16B). Row t = c>>3 = r*64 + w*8 + (l>>3), slot s = c&7 = l&7.
    // Slot s of row t holds global k4-chunk (s ^ (t&7)), t&7 = l>>3
    //   -> pre-swizzled source address, linear LDS dest.
    const int trow = l >> 3;
    const int kswz = ((l & 7) ^ trow) << 2;        // float offset
    const float* gs = X + (size_t)(T0 + w * 8 + trow) * HDIM + k0 + kswz;

#define STAGE(buf_, it_) do {                                                   \
    const size_t go_ = (size_t)(it_) * BK;                                      \
    _Pragma("unroll")                                                           \
    for (int r_ = 0; r_ < 4; ++r_)                                              \
        __builtin_amdgcn_global_load_lds(                                       \
            AS1(gs + (size_t)r_ * 64 * HDIM + go_),                             \
            AS3(&Xs[buf_][r_ * 2048 + w * 256]), 16, 0, 0);                     \
} while (0)

    float acc[4][8];
#pragma unroll
    for (int g = 0; g < 4; ++g)
#pragma unroll
        for (int j = 0; j < 8; ++j) acc[g][j] = 0.f;

    const int k4base = k0 >> 2;

    STAGE(0, 0);   // prologue

    for (int it = 0; it < NIT; ++it) {
        __syncthreads();   // drains this iter's staging loads (vmcnt) + barrier
        if (it + 1 < NIT) STAGE((it + 1) & 1, it + 1);

        const float* xb = Xs[it & 1];
        const int k4it  = k4base + it * (BK / 4);
#pragma unroll
        for (int kq = 0; kq < 8; ++kq) {
            // 128 B of W for 8 experts x 4 k, wave-uniform -> scalar loads
            const float* wp = Wp + ((size_t)(k4it + kq) * ENUM + E0) * 4;
            const wvec16 wa = *(const wvec16*)(wp);
            const wvec16 wb = *(const wvec16*)(wp + 16);
            const int slot = (kq ^ lm7) << 2;      // swizzled float4 slot
#pragma unroll
            for (int g = 0; g < 4; ++g) {
                const float4 xv = *(const float4*)(xb + (g * 64 + l) * BK + slot);
#pragma unroll
                for (int j = 0; j < 4; ++j) {
                    acc[g][j] = fmaf(xv.x, wa[4 * j + 0], acc[g][j]);
                    acc[g][j] = fmaf(xv.y, wa[4 * j + 1], acc[g][j]);
                    acc[g][j] = fmaf(xv.z, wa[4 * j + 2], acc[g][j]);
                    acc[g][j] = fmaf(xv.w, wa[4 * j + 3], acc[g][j]);
                }
#pragma unroll
                for (int j = 0; j < 4; ++j) {
                    acc[g][4 + j] = fmaf(xv.x, wb[4 * j + 0], acc[g][4 + j]);
                    acc[g][4 + j] = fmaf(xv.y, wb[4 * j + 1], acc[g][4 + j]);
                    acc[g][4 + j] = fmaf(xv.z, wb[4 * j + 2], acc[g][4 + j]);
                    acc[g][4 + j] = fmaf(xv.w, wb[4 * j + 3], acc[g][4 + j]);
                }
            }
        }
    }

    float* dst = lp + (size_t)slice * TTOK * ENUM + (size_t)(T0 + l) * ENUM + E0;
#pragma unroll
    for (int g = 0; g < 4; ++g) {
        float* d = dst + (size_t)g * 64 * ENUM;
        *(float4*)(d + 0) = make_float4(acc[g][0], acc[g][1], acc[g][2], acc[g][3]);
        *(float4*)(d + 4) = make_float4(acc[g][4], acc[g][5], acc[g][6], acc[g][7]);
    }
#undef STAGE
}

// ---------------------------------------------------------------------------
// Kernel 2: thread-per-token router. 64 tokens/block, 256 blocks.
// (unchanged except KSPLIT=8 partial sum)
// ---------------------------------------------------------------------------
#define RTOK 64
__global__ __launch_bounds__(256)
void router_topk(const float* __restrict__ lp,
                 float* __restrict__ out_idx, float* __restrict__ out_w,
                 float* __restrict__ ssum_g, int* __restrict__ cnt_g) {
    __shared__ float Ls[RTOK * 67];
    __shared__ float s_m[RTOK], s_inv[RTOK];
    __shared__ float s_ssum[ENUM];
    __shared__ int   s_cnt[ENUM];

    const int tid = threadIdx.x;
    const int t0  = blockIdx.x * RTOK;
    if (tid < ENUM) { s_cnt[tid] = 0; s_ssum[tid] = 0.f; }

#pragma unroll
    for (int r = 0; r < 4; ++r) {
        const int q  = r * 256 + tid;
        const int t  = q >> 4, c4 = q & 15;
        const size_t base = (size_t)(t0 + t) * ENUM + c4 * 4;
        float4 v = *(const float4*)(lp + base);
#pragma unroll
        for (int h = 1; h < KSPLIT; ++h) {
            float4 u = *(const float4*)(lp + (size_t)h * TTOK * ENUM + base);
            v.x += u.x; v.y += u.y; v.z += u.z; v.w += u.w;
        }
        float* d = Ls + t * 67 + c4 * 4;
        d[0] = v.x; d[1] = v.y; d[2] = v.z; d[3] = v.w;
    }
    __syncthreads();

    if (tid < RTOK) {
        const float* row = Ls + tid * 67;

        float gm[GNUM];
#pragma unroll
        for (int g = 0; g < GNUM; ++g) {
            float mg = row[g * 8];
#pragma unroll
            for (int j = 1; j < 8; ++j) mg = fmaxf(mg, row[g * 8 + j]);
            gm[g] = mg;
        }
        float m = gm[0];
#pragma unroll
        for (int g = 1; g < GNUM; ++g) m = fmaxf(m, gm[g]);

        int selmask = 0;
#pragma unroll
        for (int g = 0; g < GNUM; ++g) {
            int rank = 0;
#pragma unroll
            for (int g2 = 0; g2 < GNUM; ++g2)
                rank += (gm[g2] > gm[g]) || (gm[g2] == gm[g] && g2 < g);
            selmask |= (rank < TGK) << g;
        }

        float v0=-1.f,v1=-1.f,v2=-1.f,v3=-1.f,v4=-1.f,v5=-1.f;
        float i0=0.f,i1=0.f,i2=0.f,i3=0.f,i4=0.f,i5=0.f;
        float s = 0.f;
#pragma unroll
        for (int e = 0; e < ENUM; ++e) {
            const float ex = __expf(row[e] - m);
            s += ex;
            const float cand = ((selmask >> (e >> 3)) & 1) ? ex : -1.0f;
            const float fe = (float)e;
            const bool b0 = cand > v0, b1 = cand > v1, b2 = cand > v2,
                       b3 = cand > v3, b4 = cand > v4, b5 = cand > v5;
            v5 = b4 ? v4 : (b5 ? cand : v5);  i5 = b4 ? i4 : (b5 ? fe : i5);
            v4 = b3 ? v3 : (b4 ? cand : v4);  i4 = b3 ? i3 : (b4 ? fe : i4);
            v3 = b2 ? v2 : (b3 ? cand : v3);  i3 = b2 ? i2 : (b3 ? fe : i3);
            v2 = b1 ? v1 : (b2 ? cand : v2);  i2 = b1 ? i1 : (b2 ? fe : i2);
            v1 = b0 ? v0 : (b1 ? cand : v1);  i1 = b0 ? i0 : (b1 ? fe : i1);
            v0 = b0 ? cand : v0;              i0 = b0 ? fe : i0;
        }
        const float invw = 1.0f / (v0 + v1 + v2 + v3 + v4 + v5);
        const int t = t0 + tid;
        float* oi = out_idx + (size_t)t * KTOP;
        float* ow = out_w   + (size_t)t * KTOP;
        oi[0]=i0; oi[1]=i1; oi[2]=i2; oi[3]=i3; oi[4]=i4; oi[5]=i5;
        ow[0]=v0*invw; ow[1]=v1*invw; ow[2]=v2*invw;
        ow[3]=v3*invw; ow[4]=v4*invw; ow[5]=v5*invw;

        atomicAdd(&s_cnt[(int)i0], 1); atomicAdd(&s_cnt[(int)i1], 1);
        atomicAdd(&s_cnt[(int)i2], 1); atomicAdd(&s_cnt[(int)i3], 1);
        atomicAdd(&s_cnt[(int)i4], 1); atomicAdd(&s_cnt[(int)i5], 1);
        s_m[tid] = m; s_inv[tid] = 1.0f / s;
    }
    __syncthreads();

    {
        const int e = tid & 63, strip = tid >> 6;
        float acc = 0.f;
#pragma unroll
        for (int i = 0; i < RTOK / 4; ++i) {
            const int t = strip * (RTOK / 4) + i;
            acc += __expf(Ls[t * 67 + e] - s_m[t]) * s_inv[t];
        }
        atomicAdd(&s_ssum[e], acc);
    }
    __syncthreads();

    const int b = t0 / SSEQ;
    if (tid < ENUM) {
        atomicAdd(&ssum_g[b * ENUM + tid], s_ssum[tid]);
        atomicAdd(&cnt_g[b * ENUM + tid], s_cnt[tid]);
    }
}

// ---------------------------------------------------------------------------
// Kernel 3: aux loss (1 block) (unchanged)
// ---------------------------------------------------------------------------
__global__ __launch_bounds__(256)
void aux_loss(const float* __restrict__ ssum_g, const int* __restrict__ cnt_g,
              float* __restrict__ out_aux) {
    const int tid = threadIdx.x;
    float v = (float)cnt_g[tid] * (float)ENUM / ((float)SSEQ * (float)KTOP)
            * (ssum_g[tid] / (float)SSEQ);
#pragma unroll
    for (int off = 32; off; off >>= 1) v += __shfl_xor(v, off);
    __shared__ float red[4];
    if ((tid & 63) == 0) red[tid >> 6] = v;
    __syncthreads();
    if (tid == 0)
        out_aux[0] = (red[0] + red[1] + red[2] + red[3]) * (ALPHAC / (float)BBATCH);
}

// ---------------------------------------------------------------------------
extern "C" void kernel_launch(void* const* d_in, const int* in_sizes, int n_in,
                              void* d_out, int out_size, void* d_ws, size_t ws_size,
                              hipStream_t stream) {
    const float* X = (const float*)d_in[0];   // [4,4096,4096] fp32
    const float* W = (const float*)d_in[1];   // [64,4096] fp32

    float* out     = (float*)d_out;
    float* out_idx = out;
    float* out_w   = out + (size_t)TTOK * KTOP;
    float* out_aux = out + (size_t)2 * TTOK * KTOP;

    float* lp     = (float*)d_ws;                        // [8][T][64] = 32 MiB
    float* Wp     = lp + (size_t)KSPLIT * TTOK * ENUM;   // [1024][64][4] = 1 MiB
    float* ssum_g = Wp + (size_t)HDIM * ENUM;            // [4][64]
    int*   cnt_g  = (int*)(ssum_g + BBATCH * ENUM);      // [4][64]

    hipMemsetAsync(ssum_g, 0, BBATCH * ENUM * (sizeof(float) + sizeof(int)), stream);

    pack_w<<<(HDIM / 4) * ENUM / 256, 256, 0, stream>>>(W, Wp);
    gate_gemm<<<512, 512, 0, stream>>>(X, Wp, lp);
    router_topk<<<TTOK / RTOK, 256, 0, stream>>>(lp, out_idx, out_w, ssum_g, cnt_g);
    aux_loss<<<1, 256, 0, stream>>>(ssum_g, cnt_g, out_aux);
}